// Round 1
// baseline (2886.004 us; speedup 1.0000x reference)
//
#include <hip/hip_runtime.h>
#include <math.h>

constexpr int NFEAT  = 512;
constexpr int NHID   = 256;
constexpr int NLABEL = 64;

// ---------------- graph preprocessing ----------------

__global__ void hist_kernel(const int* __restrict__ col, int* __restrict__ hist, int E) {
    int e = blockIdx.x * blockDim.x + threadIdx.x;
    if (e < E) atomicAdd(&hist[col[e]], 1);
}

__global__ void dinv_kernel(const int* __restrict__ hist, float* __restrict__ dinv, int n) {
    int i = blockIdx.x * blockDim.x + threadIdx.x;
    if (i < n) dinv[i] = rsqrtf((float)hist[i] + 2.0f);  // deg = in-count + self-loop weight 2
}

// single-block exclusive scan over n elements (n ~ 100K, 1024 threads)
__global__ void scan_kernel(const int* __restrict__ hist, int* __restrict__ start,
                            int* __restrict__ cursor, int n) {
    __shared__ int sm[1024];
    const int t = threadIdx.x;
    int carry = 0;
    for (int base = 0; base < n; base += 1024) {
        int i = base + t;
        int v = (i < n) ? hist[i] : 0;
        sm[t] = v;
        __syncthreads();
        for (int off = 1; off < 1024; off <<= 1) {
            int x = (t >= off) ? sm[t - off] : 0;
            __syncthreads();
            sm[t] += x;
            __syncthreads();
        }
        int incl = sm[t];
        if (i < n) {
            int ex = carry + incl - v;
            start[i] = ex;
            cursor[i] = ex;
        }
        carry += sm[1023];
        __syncthreads();
    }
    if (t == 0) start[n] = carry;
}

__global__ void scatter_kernel(const int* __restrict__ row, const int* __restrict__ col,
                               const float* __restrict__ dinv, int* __restrict__ cursor,
                               int* __restrict__ ssrc, float* __restrict__ snorm, int E) {
    int e = blockIdx.x * blockDim.x + threadIdx.x;
    if (e < E) {
        int r = row[e], c = col[e];
        int p = atomicAdd(&cursor[c], 1);
        ssrc[p] = r;
        snorm[p] = dinv[r] * dinv[c];
    }
}

__global__ void labflag_kernel(const int* __restrict__ idxl, const int* __restrict__ y,
                               int* __restrict__ flag, int L) {
    int k = blockIdx.x * blockDim.x + threadIdx.x;
    if (k < L) {
        int node = idxl[k];
        flag[node] = y[node];   // duplicates write same value -> safe
    }
}

// ---------------- fp32 tiled GEMM: C[M,256] = A[M,K] @ W[K,256] (+ label rows) ----------------

template<bool LADD>
__global__ __launch_bounds__(256) void gemm64_kernel(
    const float* __restrict__ A, const float* __restrict__ W,
    float* __restrict__ C, int M, int K,
    const float* __restrict__ Wlab, const int* __restrict__ labflag) {
    __shared__ float As[16][65];
    __shared__ float Bs[16][65];
    const int t = threadIdx.x;
    const int row0 = blockIdx.x * 64;
    const int col0 = blockIdx.y * 64;
    const int tx = t & 15, ty = t >> 4;
    // A load: one float4 per thread: row ar, k-chunk ak4
    const int ar = t >> 2, ak4 = (t & 3) * 4;
    // B load: one float4 per thread
    const int bk = t >> 4, bc = (t & 15) * 4;

    float acc[4][4] = {};
    for (int k0 = 0; k0 < K; k0 += 16) {
        float4 av = make_float4(0.f, 0.f, 0.f, 0.f);
        if (row0 + ar < M)
            av = *reinterpret_cast<const float4*>(&A[(size_t)(row0 + ar) * K + k0 + ak4]);
        As[ak4 + 0][ar] = av.x; As[ak4 + 1][ar] = av.y;
        As[ak4 + 2][ar] = av.z; As[ak4 + 3][ar] = av.w;
        float4 bv = *reinterpret_cast<const float4*>(&W[(size_t)(k0 + bk) * NHID + col0 + bc]);
        Bs[bk][bc + 0] = bv.x; Bs[bk][bc + 1] = bv.y;
        Bs[bk][bc + 2] = bv.z; Bs[bk][bc + 3] = bv.w;
        __syncthreads();
        #pragma unroll
        for (int kk = 0; kk < 16; ++kk) {
            float a[4], b[4];
            #pragma unroll
            for (int i = 0; i < 4; ++i) a[i] = As[kk][ty * 4 + i];
            #pragma unroll
            for (int j = 0; j < 4; ++j) b[j] = Bs[kk][tx * 4 + j];
            #pragma unroll
            for (int i = 0; i < 4; ++i)
                #pragma unroll
                for (int j = 0; j < 4; ++j) acc[i][j] += a[i] * b[j];
        }
        __syncthreads();
    }
    #pragma unroll
    for (int i = 0; i < 4; ++i) {
        int r = row0 + ty * 4 + i;
        if (r >= M) continue;
        int flag = -1;
        if (LADD) flag = labflag[r];
        #pragma unroll
        for (int j = 0; j < 4; ++j) {
            int c = col0 + tx * 4 + j;
            float v = acc[i][j];
            if (LADD && flag >= 0) v += Wlab[(size_t)flag * NHID + c];
            C[(size_t)r * NHID + c] = v;
        }
    }
}

// ---------------- per-node aggregation: h = relu(A_norm @ z + b) ----------------

__global__ __launch_bounds__(256) void agg_kernel(
    const float* __restrict__ Z, const int* __restrict__ start,
    const int* __restrict__ ssrc, const float* __restrict__ snorm,
    const float* __restrict__ dinv, const float* __restrict__ bias,
    float* __restrict__ Hout, int M) {
    __shared__ int   s_src[256];
    __shared__ float s_nrm[256];
    const int n = blockIdx.x;
    const int t = threadIdx.x;
    const float di = dinv[n];
    float acc = (2.0f * di * di) * Z[(size_t)n * NHID + t];   // self loop (weight 2)
    const int s = start[n], e = start[n + 1];
    for (int base = s; base < e; base += 256) {
        int cnt = min(256, e - base);
        if (t < cnt) {
            s_src[t] = ssrc[base + t];
            s_nrm[t] = snorm[base + t];
        }
        __syncthreads();
        for (int i = 0; i < cnt; ++i)
            acc += s_nrm[i] * Z[(size_t)s_src[i] * NHID + t];
        __syncthreads();
    }
    Hout[(size_t)n * NHID + t] = fmaxf(acc + bias[t], 0.0f);
}

// ---------------- fused MLP head + log_softmax ----------------
// 16 rows per block, 256 threads.

__global__ __launch_bounds__(256) void mlp_kernel(
    const float* __restrict__ H, const float* __restrict__ Wm0, const float* __restrict__ bm0,
    const float* __restrict__ Wm1, const float* __restrict__ bm1,
    float* __restrict__ out, int M) {
    __shared__ float Ah[16][NHID];        // 16 KB
    __shared__ float Hm[16][2 * NHID];    // 32 KB
    const int t = threadIdx.x;
    const int row0 = blockIdx.x * 16;

    #pragma unroll
    for (int i = 0; i < 16; ++i)
        Ah[i][t] = (row0 + i < M) ? H[(size_t)(row0 + i) * NHID + t] : 0.0f;
    __syncthreads();

    // hidden = elu(Ah @ Wm0 + bm0), [16][512]
    {
        const int cg = t & 127;   // column lane
        const int rg = t >> 7;    // 0/1 -> rows rg*8 .. rg*8+7
        float acc[8][4] = {};
        for (int k = 0; k < NHID; ++k) {
            float w[4];
            #pragma unroll
            for (int j = 0; j < 4; ++j) w[j] = Wm0[(size_t)k * 512 + cg + 128 * j];
            #pragma unroll
            for (int i = 0; i < 8; ++i) {
                float a = Ah[rg * 8 + i][k];
                #pragma unroll
                for (int j = 0; j < 4; ++j) acc[i][j] += a * w[j];
            }
        }
        #pragma unroll
        for (int i = 0; i < 8; ++i)
            #pragma unroll
            for (int j = 0; j < 4; ++j) {
                int c = cg + 128 * j;
                float v = acc[i][j] + bm0[c];
                Hm[rg * 8 + i][c] = v > 0.0f ? v : expm1f(v);
            }
    }
    __syncthreads();

    // logits = Hm @ Wm1 + bm1, then log_softmax per row (one wave owns each row)
    const int c   = t & 63;
    const int rg4 = t >> 6;   // wave id 0..3; wave w handles rows w, w+4, w+8, w+12
    float acc2[4] = {};
    for (int k = 0; k < 512; ++k) {
        float w = Wm1[(size_t)k * 64 + c];
        #pragma unroll
        for (int i = 0; i < 4; ++i) acc2[i] += Hm[rg4 + 4 * i][k] * w;
    }
    #pragma unroll
    for (int i = 0; i < 4; ++i) {
        float v = acc2[i] + bm1[c];
        float m = v;
        #pragma unroll
        for (int off = 32; off; off >>= 1) m = fmaxf(m, __shfl_xor(m, off));
        float s = expf(v - m);
        #pragma unroll
        for (int off = 32; off; off >>= 1) s += __shfl_xor(s, off);
        int r = row0 + rg4 + 4 * i;
        if (r < M) out[(size_t)r * NLABEL + c] = v - m - logf(s);
    }
}

// ---------------- launch ----------------

extern "C" void kernel_launch(void* const* d_in, const int* in_sizes, int n_in,
                              void* d_out, int out_size, void* d_ws, size_t ws_size,
                              hipStream_t stream) {
    const float* x   = (const float*)d_in[0];
    const int*   y   = (const int*)  d_in[1];
    const int*   adj = (const int*)  d_in[3];
    const int*   idxl= (const int*)  d_in[4];
    const float* W0  = (const float*)d_in[6];
    const float* b0  = (const float*)d_in[7];
    const float* W1  = (const float*)d_in[8];
    const float* b1  = (const float*)d_in[9];
    const float* W2  = (const float*)d_in[10];
    const float* b2  = (const float*)d_in[11];
    const float* Wm0 = (const float*)d_in[12];
    const float* bm0 = (const float*)d_in[13];
    const float* Wm1 = (const float*)d_in[14];
    const float* bm1 = (const float*)d_in[15];

    const int N = in_sizes[0] / NFEAT;
    const int E = in_sizes[3] / 2;
    const int L = in_sizes[4];
    const int* erow = adj;       // message sources
    const int* ecol = adj + E;   // aggregation targets

    char* ws = (char*)d_ws;
    size_t off = 0;
    auto alloc = [&](size_t bytes) -> void* {
        void* p = ws + off;
        off += (bytes + 255) & ~(size_t)255;
        return p;
    };
    float* bufA   = (float*)alloc((size_t)N * NHID * 4);
    float* bufB   = (float*)alloc((size_t)N * NHID * 4);
    int*   hist   = (int*)  alloc((size_t)N * 4);
    int*   startA = (int*)  alloc((size_t)(N + 1) * 4);
    int*   cursor = (int*)  alloc((size_t)N * 4);
    float* dinv   = (float*)alloc((size_t)N * 4);
    int*   lflag  = (int*)  alloc((size_t)N * 4);
    int*   ssrc   = (int*)  alloc((size_t)E * 4);
    float* snorm  = (float*)alloc((size_t)E * 4);
    (void)ws_size;

    hipMemsetAsync(hist, 0, (size_t)N * 4, stream);
    hipMemsetAsync(lflag, 0xFF, (size_t)N * 4, stream);   // -1

    const int TB = 256;
    hist_kernel<<<(E + TB - 1) / TB, TB, 0, stream>>>(ecol, hist, E);
    dinv_kernel<<<(N + TB - 1) / TB, TB, 0, stream>>>(hist, dinv, N);
    scan_kernel<<<1, 1024, 0, stream>>>(hist, startA, cursor, N);
    scatter_kernel<<<(E + TB - 1) / TB, TB, 0, stream>>>(erow, ecol, dinv, cursor, ssrc, snorm, E);
    labflag_kernel<<<(L + TB - 1) / TB, TB, 0, stream>>>(idxl, y, lflag, L);

    dim3 ggrid((N + 63) / 64, NHID / 64);
    // layer 0: z = x @ W0[:512] (+ label rows W0[512+flag]); agg -> bufA
    gemm64_kernel<true ><<<ggrid, 256, 0, stream>>>(x,    W0, bufB, N, NFEAT, W0 + (size_t)NFEAT * NHID, lflag);
    agg_kernel<<<N, 256, 0, stream>>>(bufB, startA, ssrc, snorm, dinv, b0, bufA, N);
    // layer 1
    gemm64_kernel<false><<<ggrid, 256, 0, stream>>>(bufA, W1, bufB, N, NHID, nullptr, nullptr);
    agg_kernel<<<N, 256, 0, stream>>>(bufB, startA, ssrc, snorm, dinv, b1, bufA, N);
    // layer 2
    gemm64_kernel<false><<<ggrid, 256, 0, stream>>>(bufA, W2, bufB, N, NHID, nullptr, nullptr);
    agg_kernel<<<N, 256, 0, stream>>>(bufB, startA, ssrc, snorm, dinv, b2, bufA, N);
    // MLP head + log_softmax -> d_out
    mlp_kernel<<<(N + 15) / 16, 256, 0, stream>>>(bufA, Wm0, bm0, Wm1, bm1, (float*)d_out, N);
}

// Round 2
// 1166.482 us; speedup vs baseline: 2.4741x; 2.4741x over previous
//
#include <hip/hip_runtime.h>
#include <math.h>

using f32x4  = __attribute__((ext_vector_type(4))) float;
using bf16x8 = __attribute__((ext_vector_type(8))) short;

constexpr int NFEAT = 512;
constexpr int NHID  = 256;
constexpr int NLAB  = 64;

__device__ __forceinline__ unsigned short f2bf(float f) {
    unsigned int u = __float_as_uint(f);
    u += 0x7FFFu + ((u >> 16) & 1u);          // RNE
    return (unsigned short)(u >> 16);
}
__device__ __forceinline__ float bf2f(unsigned short s) {
    return __uint_as_float(((unsigned int)s) << 16);
}
__device__ __forceinline__ void gload_lds16(const void* g, void* l) {
    __builtin_amdgcn_global_load_lds(
        (const __attribute__((address_space(1))) unsigned int*)g,
        (__attribute__((address_space(3))) unsigned int*)l, 16, 0, 0);
}

// ---------------- graph preprocessing ----------------

__global__ void hist_kernel(const int* __restrict__ col, int* __restrict__ hist, int E) {
    int e = blockIdx.x * blockDim.x + threadIdx.x;
    if (e < E) atomicAdd(&hist[col[e]], 1);
}

__global__ void dinv_kernel(const int* __restrict__ hist, float* __restrict__ dinv, int n) {
    int i = blockIdx.x * blockDim.x + threadIdx.x;
    if (i < n) dinv[i] = rsqrtf((float)hist[i] + 2.0f);  // deg = in-count + self-loop weight 2
}

// 3-phase scan: per-block scan -> block-sum scan -> add offsets
__global__ void scan1_kernel(const int* __restrict__ hist, int* __restrict__ start,
                             int* __restrict__ bsum, int n) {
    __shared__ int sm[1024];
    const int t = threadIdx.x;
    const int i = blockIdx.x * 1024 + t;
    int v = (i < n) ? hist[i] : 0;
    sm[t] = v;
    __syncthreads();
    for (int off = 1; off < 1024; off <<= 1) {
        int x2 = (t >= off) ? sm[t - off] : 0;
        __syncthreads();
        sm[t] += x2;
        __syncthreads();
    }
    start[i] = sm[t] - v;                       // block-local exclusive
    if (t == 1023) bsum[blockIdx.x] = sm[1023];
}

__global__ void scan2_kernel(int* __restrict__ bsum, int nb) {
    __shared__ int sm[1024];
    const int t = threadIdx.x;
    int v = (t < nb) ? bsum[t] : 0;
    sm[t] = v;
    __syncthreads();
    for (int off = 1; off < 1024; off <<= 1) {
        int x2 = (t >= off) ? sm[t - off] : 0;
        __syncthreads();
        sm[t] += x2;
        __syncthreads();
    }
    if (t < nb) bsum[t] = sm[t] - v;            // exclusive block offsets
}

__global__ void scan3_kernel(int* __restrict__ start, int* __restrict__ cursor,
                             const int* __restrict__ bsum, int P) {
    int i = blockIdx.x * blockDim.x + threadIdx.x;
    if (i < P) {
        int v = start[i] + bsum[i >> 10];
        start[i] = v;
        if (i < P - 1) cursor[i] = v;
    }
}

__global__ void scatter_kernel(const int* __restrict__ row, const int* __restrict__ col,
                               const float* __restrict__ dinv, int* __restrict__ cursor,
                               int* __restrict__ ssrc, float* __restrict__ snorm, int E) {
    int e = blockIdx.x * blockDim.x + threadIdx.x;
    if (e < E) {
        int r = row[e], c = col[e];
        int p = atomicAdd(&cursor[c], 1);
        ssrc[p] = r;
        snorm[p] = dinv[r] * dinv[c];
    }
}

__global__ void labflag_kernel(const int* __restrict__ idxl, const int* __restrict__ y,
                               int* __restrict__ flag, int L) {
    int k = blockIdx.x * blockDim.x + threadIdx.x;
    if (k < L) {
        int node = idxl[k];
        flag[node] = y[node];
    }
}

// ---------------- weight convert / transpose to bf16 ----------------

// out[n*K + k] = bf16(in[k*Nc + n])   (out is [Nc][K])
__global__ void convT_kernel(const float* __restrict__ in, unsigned short* __restrict__ out,
                             int K, int Nc) {
    int idx = blockIdx.x * blockDim.x + threadIdx.x;
    if (idx < K * Nc) {
        int n = idx / K, k = idx - n * K;
        out[idx] = f2bf(in[(size_t)k * Nc + n]);
    }
}

__global__ void conv_kernel(const float* __restrict__ in, unsigned short* __restrict__ out, int total) {
    int idx = blockIdx.x * blockDim.x + threadIdx.x;
    if (idx < total) out[idx] = f2bf(in[idx]);
}

// ---------------- bf16 MFMA GEMM: C[M,N] = A[M,K] @ Bt[N,K]^T ----------------
// 128x128 tile, BK=64, 4 waves (2x2), global_load_lds staging with
// source-side XOR swizzle (kg ^= row&7) so ds_read_b128 is conflict-free.
// EPI: 0 = plain bf16 store; 1 = + label-row add (layer 0); 2 = +bias, ELU (MLP hidden)
// AF32: A is fp32 (layer 0 reads x directly, reg-staged convert)

template<int EPI, bool AF32>
__global__ __launch_bounds__(256) void mfma_gemm(
    const unsigned short* __restrict__ A, const float* __restrict__ Af,
    const unsigned short* __restrict__ Bt, unsigned short* __restrict__ C,
    int M, int K, int N,
    const int* __restrict__ lflag, const unsigned short* __restrict__ Wlab,
    const float* __restrict__ bias) {
    __shared__ __align__(16) unsigned short lsA[128 * 64];
    __shared__ __align__(16) unsigned short lsB[128 * 64];
    const int t = threadIdx.x;
    const int wv = t >> 6, lane = t & 63;
    const int l16 = lane & 15, lk = lane >> 4;
    const int wr = wv >> 1, wc = wv & 1;
    const int row0 = blockIdx.x * 128, col0 = blockIdx.y * 128;

    f32x4 acc[4][4];
    const f32x4 fz = {0.f, 0.f, 0.f, 0.f};
    #pragma unroll
    for (int m = 0; m < 4; ++m)
        #pragma unroll
        for (int n = 0; n < 4; ++n) acc[m][n] = fz;

    for (int k0 = 0; k0 < K; k0 += 64) {
        // stage A tile (128 rows x 64 k)
        #pragma unroll
        for (int q = 0; q < 4; ++q) {
            const int bc = wv * 256 + q * 64;     // wave-uniform base chunk
            const int c = bc + lane;
            const int row = c >> 3;
            const int kg = (c & 7) ^ (row & 7);
            const int arow = min(row0 + row, M - 1);
            if (AF32) {
                const float* src = Af + (size_t)arow * K + k0 + kg * 8;
                float4 f0 = *(const float4*)src;
                float4 f1 = *(const float4*)(src + 4);
                bf16x8 p;
                p[0] = (short)f2bf(f0.x); p[1] = (short)f2bf(f0.y);
                p[2] = (short)f2bf(f0.z); p[3] = (short)f2bf(f0.w);
                p[4] = (short)f2bf(f1.x); p[5] = (short)f2bf(f1.y);
                p[6] = (short)f2bf(f1.z); p[7] = (short)f2bf(f1.w);
                *(bf16x8*)&lsA[(size_t)c * 8] = p;
            } else {
                gload_lds16(A + (size_t)arow * K + k0 + kg * 8, &lsA[(size_t)bc * 8]);
            }
        }
        // stage B tile (128 out-cols x 64 k) — Bt is [N][K]
        #pragma unroll
        for (int q = 0; q < 4; ++q) {
            const int bc = wv * 256 + q * 64;
            const int c = bc + lane;
            const int row = c >> 3;
            const int kg = (c & 7) ^ (row & 7);
            gload_lds16(Bt + (size_t)(col0 + row) * K + k0 + kg * 8, &lsB[(size_t)bc * 8]);
        }
        __syncthreads();
        #pragma unroll
        for (int kk = 0; kk < 2; ++kk) {
            bf16x8 a[4], b[4];
            #pragma unroll
            for (int m = 0; m < 4; ++m) {
                const int row = wr * 64 + m * 16 + l16;
                const int cc = row * 8 + ((kk * 4 + lk) ^ (row & 7));
                a[m] = *(const bf16x8*)&lsA[(size_t)cc * 8];
            }
            #pragma unroll
            for (int n = 0; n < 4; ++n) {
                const int row = wc * 64 + n * 16 + l16;
                const int cc = row * 8 + ((kk * 4 + lk) ^ (row & 7));
                b[n] = *(const bf16x8*)&lsB[(size_t)cc * 8];
            }
            #pragma unroll
            for (int m = 0; m < 4; ++m)
                #pragma unroll
                for (int n = 0; n < 4; ++n)
                    acc[m][n] = __builtin_amdgcn_mfma_f32_16x16x32_bf16(a[m], b[n], acc[m][n], 0, 0, 0);
        }
        __syncthreads();
    }

    // epilogue: C/D layout col=lane&15, row=(lane>>4)*4+reg
    #pragma unroll
    for (int m = 0; m < 4; ++m) {
        #pragma unroll
        for (int r = 0; r < 4; ++r) {
            const int grow = row0 + wr * 64 + m * 16 + lk * 4 + r;
            if (grow >= M) continue;
            int flag = -1;
            if (EPI == 1) flag = lflag[grow];
            #pragma unroll
            for (int n = 0; n < 4; ++n) {
                const int gcol = col0 + wc * 64 + n * 16 + l16;
                float v = acc[m][n][r];
                if (EPI == 1) { if (flag >= 0) v += bf2f(Wlab[flag * NHID + gcol]); }
                if (EPI == 2) { v += bias[gcol]; v = v > 0.f ? v : expm1f(v); }
                C[(size_t)grow * N + gcol] = f2bf(v);
            }
        }
    }
}

// ---------------- per-node aggregation (bf16 Z -> bf16 H) ----------------
// one wave per node (avg degree 16); lane covers 4 columns.

__global__ __launch_bounds__(256) void agg_bf16(
    const unsigned short* __restrict__ Z, const int* __restrict__ start,
    const int* __restrict__ ssrc, const float* __restrict__ snorm,
    const float* __restrict__ dinv, const float* __restrict__ bias,
    unsigned short* __restrict__ H, int M) {
    const int t = threadIdx.x;
    const int node = blockIdx.x * 4 + (t >> 6);
    if (node >= M) return;
    const int lane = t & 63;
    const int c0 = lane * 4;
    const float di = dinv[node];
    float a0, a1, a2, a3;
    {
        const float sw = 2.f * di * di;                  // self-loop weight 2
        ushort4 z = *(const ushort4*)&Z[(size_t)node * NHID + c0];
        a0 = sw * bf2f(z.x); a1 = sw * bf2f(z.y);
        a2 = sw * bf2f(z.z); a3 = sw * bf2f(z.w);
    }
    const int s = start[node], e = start[node + 1];
    for (int base = s; base < e; base += 64) {
        const int cnt = min(64, e - base);
        int msrc = 0; float mnrm = 0.f;
        if (lane < cnt) { msrc = ssrc[base + lane]; mnrm = snorm[base + lane]; }
        for (int i = 0; i < cnt; ++i) {
            const int src = __shfl(msrc, i);
            const float nr = __shfl(mnrm, i);
            ushort4 zv = *(const ushort4*)&Z[(size_t)src * NHID + c0];
            a0 += nr * bf2f(zv.x); a1 += nr * bf2f(zv.y);
            a2 += nr * bf2f(zv.z); a3 += nr * bf2f(zv.w);
        }
    }
    float4 bb = *(const float4*)&bias[c0];
    ushort4 o;
    o.x = f2bf(fmaxf(a0 + bb.x, 0.f)); o.y = f2bf(fmaxf(a1 + bb.y, 0.f));
    o.z = f2bf(fmaxf(a2 + bb.z, 0.f)); o.w = f2bf(fmaxf(a3 + bb.w, 0.f));
    *(ushort4*)&H[(size_t)node * NHID + c0] = o;
}

// ---------------- logits GEMM (M x 512 x 64) + fused log_softmax ----------------
// 128 rows/block, 4 waves (32 rows each), full 64-col output per wave.

__global__ __launch_bounds__(256) void logits_kernel(
    const unsigned short* __restrict__ A, const unsigned short* __restrict__ Bt,
    const float* __restrict__ bias, float* __restrict__ out, int M) {
    __shared__ __align__(16) unsigned short lsA[128 * 64];
    __shared__ __align__(16) unsigned short lsB[64 * 64];
    const int t = threadIdx.x;
    const int wv = t >> 6, lane = t & 63;
    const int l16 = lane & 15, lk = lane >> 4;
    const int row0 = blockIdx.x * 128;

    f32x4 acc[2][4];
    const f32x4 fz = {0.f, 0.f, 0.f, 0.f};
    #pragma unroll
    for (int m = 0; m < 2; ++m)
        #pragma unroll
        for (int n = 0; n < 4; ++n) acc[m][n] = fz;

    for (int k0 = 0; k0 < 512; k0 += 64) {
        #pragma unroll
        for (int q = 0; q < 4; ++q) {
            const int bc = wv * 256 + q * 64;
            const int c = bc + lane;
            const int row = c >> 3;
            const int kg = (c & 7) ^ (row & 7);
            gload_lds16(A + (size_t)min(row0 + row, M - 1) * 512 + k0 + kg * 8,
                        &lsA[(size_t)bc * 8]);
        }
        #pragma unroll
        for (int q = 0; q < 2; ++q) {
            const int bc = wv * 128 + q * 64;
            const int c = bc + lane;
            const int row = c >> 3;
            const int kg = (c & 7) ^ (row & 7);
            gload_lds16(Bt + (size_t)row * 512 + k0 + kg * 8, &lsB[(size_t)bc * 8]);
        }
        __syncthreads();
        #pragma unroll
        for (int kk = 0; kk < 2; ++kk) {
            bf16x8 a[2], b[4];
            #pragma unroll
            for (int m = 0; m < 2; ++m) {
                const int row = wv * 32 + m * 16 + l16;
                const int cc = row * 8 + ((kk * 4 + lk) ^ (row & 7));
                a[m] = *(const bf16x8*)&lsA[(size_t)cc * 8];
            }
            #pragma unroll
            for (int n = 0; n < 4; ++n) {
                const int row = n * 16 + l16;
                const int cc = row * 8 + ((kk * 4 + lk) ^ (row & 7));
                b[n] = *(const bf16x8*)&lsB[(size_t)cc * 8];
            }
            #pragma unroll
            for (int m = 0; m < 2; ++m)
                #pragma unroll
                for (int n = 0; n < 4; ++n)
                    acc[m][n] = __builtin_amdgcn_mfma_f32_16x16x32_bf16(a[m], b[n], acc[m][n], 0, 0, 0);
        }
        __syncthreads();
    }

    #pragma unroll
    for (int m = 0; m < 2; ++m) {
        #pragma unroll
        for (int r = 0; r < 4; ++r) {
            const int grow = row0 + wv * 32 + m * 16 + lk * 4 + r;
            float v[4];
            float mx = -3.4e38f;
            #pragma unroll
            for (int n = 0; n < 4; ++n) {
                v[n] = acc[m][n][r] + bias[n * 16 + l16];
                mx = fmaxf(mx, v[n]);
            }
            #pragma unroll
            for (int off = 1; off < 16; off <<= 1) mx = fmaxf(mx, __shfl_xor(mx, off));
            float s = 0.f;
            #pragma unroll
            for (int n = 0; n < 4; ++n) s += expf(v[n] - mx);
            #pragma unroll
            for (int off = 1; off < 16; off <<= 1) s += __shfl_xor(s, off);
            const float ls = logf(s);
            if (grow < M) {
                #pragma unroll
                for (int n = 0; n < 4; ++n)
                    out[(size_t)grow * NLAB + n * 16 + l16] = v[n] - mx - ls;
            }
        }
    }
}

// ---------------- launch ----------------

extern "C" void kernel_launch(void* const* d_in, const int* in_sizes, int n_in,
                              void* d_out, int out_size, void* d_ws, size_t ws_size,
                              hipStream_t stream) {
    const float* x   = (const float*)d_in[0];
    const int*   y   = (const int*)  d_in[1];
    const int*   adj = (const int*)  d_in[3];
    const int*   idxl= (const int*)  d_in[4];
    const float* W0  = (const float*)d_in[6];
    const float* b0  = (const float*)d_in[7];
    const float* W1  = (const float*)d_in[8];
    const float* b1  = (const float*)d_in[9];
    const float* W2  = (const float*)d_in[10];
    const float* b2  = (const float*)d_in[11];
    const float* Wm0 = (const float*)d_in[12];
    const float* bm0 = (const float*)d_in[13];
    const float* Wm1 = (const float*)d_in[14];
    const float* bm1 = (const float*)d_in[15];

    const int N = in_sizes[0] / NFEAT;
    const int E = in_sizes[3] / 2;
    const int L = in_sizes[4];
    const int* erow = adj;       // message sources
    const int* ecol = adj + E;   // aggregation targets

    char* ws = (char*)d_ws;
    size_t off = 0;
    auto alloc = [&](size_t bytes) -> void* {
        void* p = ws + off;
        off += (bytes + 255) & ~(size_t)255;
        return p;
    };
    const int P = N + 1;
    const int nb1 = (P + 1023) / 1024;
    unsigned short* Zb    = (unsigned short*)alloc((size_t)N * NHID * 2);
    unsigned short* Hb    = (unsigned short*)alloc((size_t)N * NHID * 2);
    int*   hist   = (int*)  alloc((size_t)N * 4);
    int*   startA = (int*)  alloc((size_t)nb1 * 1024 * 4);
    int*   cursor = (int*)  alloc((size_t)N * 4);
    float* dinv   = (float*)alloc((size_t)N * 4);
    int*   lflag  = (int*)  alloc((size_t)N * 4);
    int*   ssrc   = (int*)  alloc((size_t)E * 4);
    float* snorm  = (float*)alloc((size_t)E * 4);
    int*   bsum   = (int*)  alloc((size_t)1024 * 4);
    unsigned short* W0t   = (unsigned short*)alloc((size_t)256 * 512 * 2);
    unsigned short* W0lab = (unsigned short*)alloc((size_t)64 * 256 * 2);
    unsigned short* W1t   = (unsigned short*)alloc((size_t)256 * 256 * 2);
    unsigned short* W2t   = (unsigned short*)alloc((size_t)256 * 256 * 2);
    unsigned short* Wm0t  = (unsigned short*)alloc((size_t)512 * 256 * 2);
    unsigned short* Wm1t  = (unsigned short*)alloc((size_t)64 * 512 * 2);
    // H1 (M x 512 bf16): prefer ws; if ws is too small, reuse the x buffer
    // (x is dead after the layer-0 GEMM; harness restores d_in before every launch)
    unsigned short* H1;
    {
        size_t need = (size_t)N * 512 * 2;
        if (off + need <= ws_size) H1 = (unsigned short*)alloc(need);
        else                       H1 = (unsigned short*)(void*)d_in[0];
    }

    hipMemsetAsync(hist, 0, (size_t)N * 4, stream);
    hipMemsetAsync(lflag, 0xFF, (size_t)N * 4, stream);   // -1

    const int TB = 256;
    hist_kernel<<<(E + TB - 1) / TB, TB, 0, stream>>>(ecol, hist, E);
    dinv_kernel<<<(N + TB - 1) / TB, TB, 0, stream>>>(hist, dinv, N);
    scan1_kernel<<<nb1, 1024, 0, stream>>>(hist, startA, bsum, N);
    scan2_kernel<<<1, 1024, 0, stream>>>(bsum, nb1);
    scan3_kernel<<<(P + TB - 1) / TB, TB, 0, stream>>>(startA, cursor, bsum, P);
    scatter_kernel<<<(E + TB - 1) / TB, TB, 0, stream>>>(erow, ecol, dinv, cursor, ssrc, snorm, E);
    labflag_kernel<<<(L + TB - 1) / TB, TB, 0, stream>>>(idxl, y, lflag, L);

    convT_kernel<<<(512 * 256 + TB - 1) / TB, TB, 0, stream>>>(W0, W0t, 512, 256);
    conv_kernel <<<(64 * 256 + TB - 1) / TB, TB, 0, stream>>>(W0 + (size_t)512 * 256, W0lab, 64 * 256);
    convT_kernel<<<(256 * 256 + TB - 1) / TB, TB, 0, stream>>>(W1, W1t, 256, 256);
    convT_kernel<<<(256 * 256 + TB - 1) / TB, TB, 0, stream>>>(W2, W2t, 256, 256);
    convT_kernel<<<(256 * 512 + TB - 1) / TB, TB, 0, stream>>>(Wm0, Wm0t, 256, 512);
    convT_kernel<<<(512 * 64 + TB - 1) / TB, TB, 0, stream>>>(Wm1, Wm1t, 512, 64);

    dim3 g2((N + 127) / 128, 2), g4((N + 127) / 128, 4);
    const int aggGrid = (N + 3) / 4;
    // layer 0 (A = x fp32, K=512, + label rows)
    mfma_gemm<1, true ><<<g2, 256, 0, stream>>>(nullptr, x, W0t, Zb, N, 512, 256, lflag, W0lab, nullptr);
    agg_bf16<<<aggGrid, 256, 0, stream>>>(Zb, startA, ssrc, snorm, dinv, b0, Hb, N);
    // layer 1
    mfma_gemm<0, false><<<g2, 256, 0, stream>>>(Hb, nullptr, W1t, Zb, N, 256, 256, nullptr, nullptr, nullptr);
    agg_bf16<<<aggGrid, 256, 0, stream>>>(Zb, startA, ssrc, snorm, dinv, b1, Hb, N);
    // layer 2
    mfma_gemm<0, false><<<g2, 256, 0, stream>>>(Hb, nullptr, W2t, Zb, N, 256, 256, nullptr, nullptr, nullptr);
    agg_bf16<<<aggGrid, 256, 0, stream>>>(Zb, startA, ssrc, snorm, dinv, b2, Hb, N);
    // MLP hidden: H1 = elu(Hb @ Wm0 + bm0), N=512
    mfma_gemm<2, false><<<g4, 256, 0, stream>>>(Hb, nullptr, Wm0t, H1, N, 256, 512, nullptr, nullptr, bm0);
    // logits + log_softmax
    logits_kernel<<<(N + 127) / 128, 256, 0, stream>>>(H1, Wm1t, bm1, (float*)d_out, N);
}